// Round 5
// baseline (151.593 us; speedup 1.0000x reference)
//
#include <hip/hip_runtime.h>
#include <hip/hip_fp16.h>
#include <math.h>

#define NA_ 10000
#define NM_ 150000
#define B_  4
#define NS_ 4
#define NMAX_ 32
#define NO_ 4
#define H1_ 4
#define H2_ 38
#define NBLK_ (NM_ / 4)          // 4-pair blocks per image
#define PI_F 3.14159265358979323846f

// ---- ws layout (main path) ----
#define CSN_OFF   ((size_t)0)
#define CSN_BYTES ((size_t)B_ * NA_ * NMAX_ * 4)       // 5,120,000
#define REC_OFF   (CSN_OFF + CSN_BYTES)
#define REC_BYTES ((size_t)B_ * NM_ * 16)              // 9,600,000
#define R4_OFF    (REC_OFF + REC_BYTES)
#define R4_BYTES  ((size_t)B_ * NBLK_ * NMAX_ * 8)     // 38,400,000
#define ST_OFF    (R4_OFF + R4_BYTES)
#define ST_BYTES  ((size_t)B_ * (NA_ + 1) * 4 + 16)
#define WS_NEED   (ST_OFF + ST_BYTES)

// ---------------------------------------------------------------------------
// Kernel 0: segment starts from sorted iidx.
// ---------------------------------------------------------------------------
__global__ void starts_kernel(const int* __restrict__ iidx, int* __restrict__ starts) {
    int p = blockIdx.x * blockDim.x + threadIdx.x;
    if (p >= B_ * NM_) return;
    int b = p / NM_, pl = p - b * NM_;
    const int* ii = iidx + (size_t)b * NM_;
    int* st = starts + (size_t)b * (NA_ + 1);
    int cur = ii[pl];
    int prev = (pl == 0) ? -1 : ii[pl - 1];
    for (int a = prev + 1; a <= cur; ++a) st[a] = pl;
    if (pl == NM_ - 1) {
        for (int a = cur + 1; a <= NA_; ++a) st[a] = NM_;
    }
}

// ---------------------------------------------------------------------------
// prep0: per 4-pair block, write R4[b][blk][n] = ushort4 of fp16 radials and
// rec[p] = (x, y, z, bitcast jat). One block per 32-lane half-wave.
// ---------------------------------------------------------------------------
__global__ __launch_bounds__(256) void prep0_kernel(
    const float* __restrict__ disp, const float* __restrict__ alpha,
    const float* __restrict__ rsp, const int* __restrict__ jidx,
    const int* __restrict__ sorted_numbers,
    ushort4* __restrict__ R4, float4* __restrict__ rec)
{
    int wid = (blockIdx.x * 256 + threadIdx.x) >> 6;
    int lane = threadIdx.x & 63;
    int h = lane >> 5, n = lane & 31;
    int gh = wid * 2 + h;                 // [0, B*NBLK)
    int b = gh / NBLK_;
    int blk = gh - b * NBLK_;
    int pbase = blk * 4;

    float al0 = alpha[n],      al1 = alpha[32 + n];
    float al2 = alpha[64 + n], al3 = alpha[96 + n];
    float rv0 = rsp[n],        rv1 = rsp[32 + n];
    float rv2 = rsp[64 + n],   rv3 = rsp[96 + n];

    const int* jjb = jidx + (size_t)b * NM_;
    const float* dpb = disp + (size_t)b * NM_ * 3;

    float xs0, ys0, zs0, xs1, ys1, zs1, xs2, ys2, zs2, xs3, ys3, zs3;
    int jt0, jt1, jt2, jt3;
    float rr0, rr1, rr2, rr3;

#define PREP_PAIR(K, XS, YS, ZS, JT, RR)                                   \
    {                                                                      \
        int p = pbase + (K);                                               \
        int j = jjb[p];                                                    \
        XS = dpb[p * 3 + 0]; YS = dpb[p * 3 + 1]; ZS = dpb[p * 3 + 2];     \
        JT = sorted_numbers[j];                                            \
        float dist = sqrtf(XS * XS + YS * YS + ZS * ZS);                   \
        float c = __cosf(dist * (PI_F / 6.0f));                            \
        float fc = 0.25f * (c + 1.f) * (c + 1.f);                          \
        bool s0 = (JT & 1) != 0, s1 = (JT & 2) != 0;                       \
        float av = s1 ? (s0 ? al3 : al2) : (s0 ? al1 : al0);               \
        float rv = s1 ? (s0 ? rv3 : rv2) : (s0 ? rv1 : rv0);               \
        float dd = dist - rv;                                              \
        RR = fc * __expf(av * dd * dd);                                    \
    }
    PREP_PAIR(0, xs0, ys0, zs0, jt0, rr0)
    PREP_PAIR(1, xs1, ys1, zs1, jt1, rr1)
    PREP_PAIR(2, xs2, ys2, zs2, jt2, rr2)
    PREP_PAIR(3, xs3, ys3, zs3, jt3, rr3)
#undef PREP_PAIR

    ushort4 w;
    w.x = __half_as_ushort(__float2half_rn(rr0));
    w.y = __half_as_ushort(__float2half_rn(rr1));
    w.z = __half_as_ushort(__float2half_rn(rr2));
    w.w = __half_as_ushort(__float2half_rn(rr3));
    R4[(size_t)gh * NMAX_ + n] = w;

    if (n < 4) {
        float sx = (n == 0) ? xs0 : (n == 1) ? xs1 : (n == 2) ? xs2 : xs3;
        float sy = (n == 0) ? ys0 : (n == 1) ? ys1 : (n == 2) ? ys2 : ys3;
        float sz = (n == 0) ? zs0 : (n == 1) ? zs1 : (n == 2) ? zs2 : zs3;
        int sj   = (n == 0) ? jt0 : (n == 1) ? jt1 : (n == 2) ? jt2 : jt3;
        rec[(size_t)b * NM_ + pbase + n] =
            make_float4(sx, sy, sz, __int_as_float(sj));
    }
}

// ---------------------------------------------------------------------------
// prep1: in-place fold R4[p][n] *= csn2[j[p]][n]. Pair-parallel, latency
// tolerant. Safe across graph replays (prep0 rewrites all of R4 each call).
// ---------------------------------------------------------------------------
__global__ __launch_bounds__(256) void prep1_kernel(
    const int* __restrict__ jidx, const float* __restrict__ csn2,
    ushort4* __restrict__ R4)
{
    int wid = (blockIdx.x * 256 + threadIdx.x) >> 6;
    int lane = threadIdx.x & 63;
    int h = lane >> 5, n = lane & 31;
    int gh = wid * 2 + h;
    int b = gh / NBLK_;
    int blk = gh - b * NBLK_;
    int pbase = blk * 4;

    const int* jjb = jidx + (size_t)b * NM_;
    const float* csb = csn2 + (size_t)b * NA_ * NMAX_;

    int j0 = jjb[pbase + 0], j1 = jjb[pbase + 1];
    int j2 = jjb[pbase + 2], j3 = jjb[pbase + 3];
    ushort4 w = R4[(size_t)gh * NMAX_ + n];
    float c0 = csb[(size_t)j0 * NMAX_ + n];
    float c1 = csb[(size_t)j1 * NMAX_ + n];
    float c2 = csb[(size_t)j2 * NMAX_ + n];
    float c3 = csb[(size_t)j3 * NMAX_ + n];
    w.x = __half_as_ushort(__float2half_rn(__half2float(__ushort_as_half(w.x)) * c0));
    w.y = __half_as_ushort(__float2half_rn(__half2float(__ushort_as_half(w.y)) * c1));
    w.z = __half_as_ushort(__float2half_rn(__half2float(__ushort_as_half(w.z)) * c2));
    w.w = __half_as_ushort(__float2half_rn(__half2float(__ushort_as_half(w.w)) * c3));
    R4[(size_t)gh * NMAX_ + n] = w;
}

// ---------------------------------------------------------------------------
// pass: ONE atom per wave. Half h walks blocks fb+h, fb+h+2, ... (8 pairs per
// wave-iteration). Per half-iteration: 1 dwordx2 (R4) + 4 dwordx4 (rec).
// Segment-edge pairs masked via cndmask; reads clamped in-bounds.
// PASS=0: coef = R * spv[jat from rec.w]; epilogue MLP -> csn2.
// PASS=1: coef = R (csn2 pre-folded); epilogue rho -> out.
// ---------------------------------------------------------------------------
template <int PASS>
__global__ __launch_bounds__(256) void pass_kernel(
    const ushort4* __restrict__ R4, const float4* __restrict__ rec,
    const float* __restrict__ spp, const float* __restrict__ op,
    const float* __restrict__ w1, const float* __restrict__ b1,
    const float* __restrict__ w2, const float* __restrict__ b2,
    const float* __restrict__ w3, const float* __restrict__ b3,
    const int* __restrict__ sorted_numbers, const int* __restrict__ starts,
    float* __restrict__ csn2, float* __restrict__ out)
{
    int g = blockIdx.x * 4 + (threadIdx.x >> 6);   // b*NA + a : one atom/wave
    if (g >= B_ * NA_) return;
    int lane = threadIdx.x & 63;
    int h = lane >> 5, n = lane & 31;
    int b = g / NA_, a = g - b * NA_;

    float sp0, sp1, sp2, sp3;
    if constexpr (PASS == 0) {
        sp0 = spp[n]; sp1 = spp[32 + n]; sp2 = spp[64 + n]; sp3 = spp[96 + n];
    }

    const float* opb = op + (size_t)PASS * 2 * NMAX_ * NO_;
    float W0[NO_], W1[NO_];
#pragma unroll
    for (int o = 0; o < NO_; ++o) {
        W0[o] = opb[(0 * NMAX_ + n) * NO_ + o];
        W1[o] = opb[(1 * NMAX_ + n) * NO_ + o];
    }

    const int* st = starts + b * (NA_ + 1);
    int p0 = st[a], p1 = st[a + 1];
    const ushort4* R4b = R4 + (size_t)b * NBLK_ * NMAX_;
    const float4* recb = rec + (size_t)b * NM_;

    float acc0 = 0.f, acc1 = 0.f, acc2 = 0.f, acc3 = 0.f;

    if (p0 < p1) {
        int fb = p0 >> 2, lb = (p1 - 1) >> 2;
        int nblk = lb - fb + 1;
        int iters = (nblk + 1) >> 1;

        int blk = fb + h;
        int blkc = (blk <= lb) ? blk : lb;
        bool bv = (blk <= lb);
        int pb = blkc * 4;
        ushort4 rw = R4b[(size_t)blkc * NMAX_ + n];
        float4 q0 = recb[pb + 0];
        float4 q1 = recb[pb + 1];
        float4 q2 = recb[pb + 2];
        float4 q3 = recb[pb + 3];

        for (int i = 0; i < iters; ++i) {
            int nb = blk + 2;
            int nbc = (nb <= lb) ? nb : lb;
            bool bvN = (nb <= lb);
            int pbN = nbc * 4;
            ushort4 rwN = R4b[(size_t)nbc * NMAX_ + n];
            float4 q0N = recb[pbN + 0];
            float4 q1N = recb[pbN + 1];
            float4 q2N = recb[pbN + 2];
            float4 q3N = recb[pbN + 3];

            float r0 = __half2float(__ushort_as_half(rw.x));
            float r1 = __half2float(__ushort_as_half(rw.y));
            float r2 = __half2float(__ushort_as_half(rw.z));
            float r3 = __half2float(__ushort_as_half(rw.w));

#define DO_PAIR(K, Q, R)                                                   \
            {                                                              \
                int p = pb + (K);                                          \
                bool v = bv && (p >= p0) && (p < p1);                      \
                float coef;                                                \
                if constexpr (PASS == 0) {                                 \
                    int jat = __float_as_int((Q).w);                       \
                    bool s0 = (jat & 1) != 0, s1 = (jat & 2) != 0;         \
                    float cj = s1 ? (s0 ? sp3 : sp2) : (s0 ? sp1 : sp0);   \
                    coef = (R) * cj;                                       \
                } else {                                                   \
                    coef = (R);                                            \
                }                                                          \
                coef = v ? coef : 0.f;                                     \
                acc0 += coef;                                              \
                acc1 = fmaf(coef, (Q).x, acc1);                            \
                acc2 = fmaf(coef, (Q).y, acc2);                            \
                acc3 = fmaf(coef, (Q).z, acc3);                            \
            }
            DO_PAIR(0, q0, r0)
            DO_PAIR(1, q1, r1)
            DO_PAIR(2, q2, r2)
            DO_PAIR(3, q3, r3)
#undef DO_PAIR

            blk = nb; bv = bvN; pb = pbN; rw = rwN;
            q0 = q0N; q1 = q1N; q2 = q2N; q3 = q3N;
        }
    }

    // fold the two halves, then butterfly over n
    acc0 += __shfl_xor(acc0, 32);
    acc1 += __shfl_xor(acc1, 32);
    acc2 += __shfl_xor(acc2, 32);
    acc3 += __shfl_xor(acc3, 32);

    float t[4][NO_];
#pragma unroll
    for (int o = 0; o < NO_; ++o) {
        t[0][o] = W0[o] * acc0;
        t[1][o] = W1[o] * acc1;
        t[2][o] = W1[o] * acc2;
        t[3][o] = W1[o] * acc3;
    }
#pragma unroll
    for (int off = 1; off < 32; off <<= 1) {
#pragma unroll
        for (int l = 0; l < 4; ++l)
#pragma unroll
            for (int o = 0; o < NO_; ++o)
                t[l][o] += __shfl_xor(t[l][o], off);
    }
    float rho[NO_];
#pragma unroll
    for (int o = 0; o < NO_; ++o)
        rho[o] = t[0][o] * t[0][o] + t[1][o] * t[1][o] +
                 t[2][o] * t[2][o] + t[3][o] * t[3][o];

    if constexpr (PASS == 1) {
        if (lane == 0) {
            *reinterpret_cast<float4*>(out + (size_t)g * NO_) =
                make_float4(rho[0], rho[1], rho[2], rho[3]);
        }
    } else {
        float h1v[H1_];
#pragma unroll
        for (int k = 0; k < H1_; ++k) {
            float s = b1[k];
#pragma unroll
            for (int o = 0; o < NO_; ++o) s = fmaf(rho[o], w1[o * H1_ + k], s);
            h1v[k] = tanhf(s);
        }
        // h2[j] on lane j (j<38); clamped elsewhere
        int jc = (lane < H2_) ? lane : (H2_ - 1);
        float s2 = b2[jc];
#pragma unroll
        for (int k = 0; k < H1_; ++k) s2 = fmaf(h1v[k], w2[k * H2_ + jc], s2);
        float hv = tanhf(s2);
        // out[n] = b3[n] + sum_j h2[j]*w3[j][n]   (full-wave shfl broadcasts)
        float on = b3[n];
#pragma unroll
        for (int j2 = 0; j2 < H2_; ++j2) {
            float hj = __shfl(hv, j2);
            on = fmaf(hj, w3[j2 * NMAX_ + n], on);
        }
        int aat = sorted_numbers[a];
        bool s0 = (aat & 1) != 0, s1 = (aat & 2) != 0;
        float basev = s1 ? (s0 ? sp3 : sp2) : (s0 ? sp1 : sp0);
        if (lane < 32) {
            csn2[(size_t)g * NMAX_ + n] = basev + on;
        }
    }
}

// ---------------------------------------------------------------------------
// Fallback pass kernel (round-2 proven code) — used if ws_size too small.
// ---------------------------------------------------------------------------
template <int PASS>
__global__ __launch_bounds__(256) void fb_pass_kernel(
    const float* __restrict__ disp, const float* __restrict__ alpha,
    const float* __restrict__ rsp, const float* __restrict__ spp,
    const float* __restrict__ op, const float* __restrict__ w1,
    const float* __restrict__ b1, const float* __restrict__ w2,
    const float* __restrict__ b2, const float* __restrict__ w3,
    const float* __restrict__ b3, const int* __restrict__ jidx,
    const int* __restrict__ sorted_numbers, const int* __restrict__ starts,
    float* __restrict__ csn2, float* __restrict__ out)
{
    int wave = blockIdx.x * 4 + (threadIdx.x >> 6);
    int lane = threadIdx.x & 63;
    int h = lane >> 5;
    int n = lane & 31;
    int g = wave * 2 + h;
    if (g >= B_ * NA_) return;
    int b = g / NA_, a = g - b * NA_;

    float al[NS_], rv[NS_], spv[NS_];
#pragma unroll
    for (int s = 0; s < NS_; ++s) {
        al[s] = alpha[s * NMAX_ + n];
        rv[s] = rsp[s * NMAX_ + n];
        spv[s] = spp[s * NMAX_ + n];
    }
    const float* opb = op + (size_t)PASS * 2 * NMAX_ * NO_;
    float W0[NO_], W1[NO_];
#pragma unroll
    for (int o = 0; o < NO_; ++o) {
        W0[o] = opb[(0 * NMAX_ + n) * NO_ + o];
        W1[o] = opb[(1 * NMAX_ + n) * NO_ + o];
    }
    const int* st = starts + b * (NA_ + 1);
    int p0 = st[a], p1 = st[a + 1];
    const int* jjb = jidx + (size_t)b * NM_;
    const float* dpb = disp + (size_t)b * NM_ * 3;
    const float* csb = csn2 + (size_t)b * NA_ * NMAX_;

    float acc0 = 0.f, acc1 = 0.f, acc2 = 0.f, acc3 = 0.f;
    for (int p = p0; p < p1; ++p) {
        int j = jjb[p];
        float x = dpb[p * 3 + 0], y = dpb[p * 3 + 1], z = dpb[p * 3 + 2];
        float dist = sqrtf(x * x + y * y + z * z);
        float c = __cosf(dist * (PI_F / 6.0f));
        float fcv = 0.25f * (c + 1.f) * (c + 1.f);
        int jat = sorted_numbers[j];
        bool s0 = (jat & 1) != 0, s1 = (jat & 2) != 0;
        float av = s1 ? (s0 ? al[3] : al[2]) : (s0 ? al[1] : al[0]);
        float rsv = s1 ? (s0 ? rv[3] : rv[2]) : (s0 ? rv[1] : rv[0]);
        float cj;
        if constexpr (PASS == 0)
            cj = s1 ? (s0 ? spv[3] : spv[2]) : (s0 ? spv[1] : spv[0]);
        else
            cj = csb[(size_t)j * NMAX_ + n];
        float dd = dist - rsv;
        float coef = fcv * cj * __expf(av * dd * dd);
        acc0 += coef;
        acc1 = fmaf(coef, x, acc1);
        acc2 = fmaf(coef, y, acc2);
        acc3 = fmaf(coef, z, acc3);
    }
    float t[4][NO_];
#pragma unroll
    for (int o = 0; o < NO_; ++o) {
        t[0][o] = W0[o] * acc0; t[1][o] = W1[o] * acc1;
        t[2][o] = W1[o] * acc2; t[3][o] = W1[o] * acc3;
    }
#pragma unroll
    for (int off = 1; off < 32; off <<= 1) {
#pragma unroll
        for (int l = 0; l < 4; ++l)
#pragma unroll
            for (int o = 0; o < NO_; ++o)
                t[l][o] += __shfl_xor(t[l][o], off);
    }
    float rho[NO_];
#pragma unroll
    for (int o = 0; o < NO_; ++o)
        rho[o] = t[0][o] * t[0][o] + t[1][o] * t[1][o] +
                 t[2][o] * t[2][o] + t[3][o] * t[3][o];
    if constexpr (PASS == 1) {
        if (n == 0)
            *reinterpret_cast<float4*>(out + (size_t)g * NO_) =
                make_float4(rho[0], rho[1], rho[2], rho[3]);
    } else {
        float h1v[H1_];
#pragma unroll
        for (int k = 0; k < H1_; ++k) {
            float s = b1[k];
#pragma unroll
            for (int o = 0; o < NO_; ++o) s = fmaf(rho[o], w1[o * H1_ + k], s);
            h1v[k] = tanhf(s);
        }
        float sa = b2[n];
        int jbi = 32 + (n < 6 ? n : 5);
        float sb = b2[jbi];
#pragma unroll
        for (int k = 0; k < H1_; ++k) {
            sa = fmaf(h1v[k], w2[k * H2_ + n], sa);
            sb = fmaf(h1v[k], w2[k * H2_ + jbi], sb);
        }
        float hva = tanhf(sa), hvb = tanhf(sb);
        float on = b3[n];
        int base_lane = h << 5;
#pragma unroll
        for (int j2 = 0; j2 < 32; ++j2)
            on = fmaf(__shfl(hva, base_lane + j2), w3[j2 * NMAX_ + n], on);
#pragma unroll
        for (int j2 = 0; j2 < 6; ++j2)
            on = fmaf(__shfl(hvb, base_lane + j2), w3[(32 + j2) * NMAX_ + n], on);
        int aat = sorted_numbers[a];
        bool t0b = (aat & 1) != 0, t1b = (aat & 2) != 0;
        float basev = t1b ? (t0b ? spv[3] : spv[2]) : (t0b ? spv[1] : spv[0]);
        csn2[(size_t)g * NMAX_ + n] = basev + on;
    }
}

extern "C" void kernel_launch(void* const* d_in, const int* in_sizes, int n_in,
                              void* d_out, int out_size, void* d_ws, size_t ws_size,
                              hipStream_t stream) {
    const float* disp = (const float*)d_in[0];
    const float* alpha = (const float*)d_in[1];
    const float* rsp = (const float*)d_in[2];
    const float* spp = (const float*)d_in[3];
    const float* op = (const float*)d_in[4];
    const float* w1 = (const float*)d_in[5];
    const float* b1 = (const float*)d_in[6];
    const float* w2 = (const float*)d_in[7];
    const float* b2 = (const float*)d_in[8];
    const float* w3 = (const float*)d_in[9];
    const float* b3 = (const float*)d_in[10];
    const int* iidx = (const int*)d_in[11];
    const int* jidx = (const int*)d_in[12];
    const int* sn = (const int*)d_in[13];
    float* out = (float*)d_out;

    int nthr = B_ * NM_;

    if (ws_size >= WS_NEED) {
        float* csn2 = (float*)((char*)d_ws + CSN_OFF);
        float4* rec = (float4*)((char*)d_ws + REC_OFF);
        ushort4* R4 = (ushort4*)((char*)d_ws + R4_OFF);
        int* starts = (int*)((char*)d_ws + ST_OFF);

        starts_kernel<<<(nthr + 255) / 256, 256, 0, stream>>>(iidx, starts);
        int pblocks = (B_ * NBLK_) / 8;         // 2 halves/wave, 4 waves/block
        prep0_kernel<<<pblocks, 256, 0, stream>>>(disp, alpha, rsp, jidx, sn, R4, rec);
        int ablocks = (B_ * NA_ + 3) / 4;       // 1 atom/wave, 4 waves/block
        pass_kernel<0><<<ablocks, 256, 0, stream>>>(R4, rec, spp, op, w1, b1, w2,
                                                    b2, w3, b3, sn, starts, csn2, out);
        prep1_kernel<<<pblocks, 256, 0, stream>>>(jidx, csn2, R4);
        pass_kernel<1><<<ablocks, 256, 0, stream>>>(R4, rec, spp, op, w1, b1, w2,
                                                    b2, w3, b3, sn, starts, csn2, out);
    } else {
        float* csn2 = (float*)d_ws;
        int* starts = (int*)((char*)d_ws + CSN_BYTES);
        int nblocks = ((B_ * NA_) / 2 + 3) / 4;
        starts_kernel<<<(nthr + 255) / 256, 256, 0, stream>>>(iidx, starts);
        fb_pass_kernel<0><<<nblocks, 256, 0, stream>>>(disp, alpha, rsp, spp, op,
                                                       w1, b1, w2, b2, w3, b3,
                                                       jidx, sn, starts, csn2, out);
        fb_pass_kernel<1><<<nblocks, 256, 0, stream>>>(disp, alpha, rsp, spp, op,
                                                       w1, b1, w2, b2, w3, b3,
                                                       jidx, sn, starts, csn2, out);
    }
}

// Round 6
// 114.183 us; speedup vs baseline: 1.3276x; 1.3276x over previous
//
#include <hip/hip_runtime.h>
#include <hip/hip_fp16.h>
#include <math.h>

#define NA_ 10000
#define NM_ 150000
#define B_  4
#define NS_ 4
#define NMAX_ 32
#define NO_ 4
#define H1_ 4
#define H2_ 38
#define PI_F 3.14159265358979323846f

// ---- ws layout (main path) ----
#define CSN_OFF   ((size_t)0)
#define CSN_BYTES ((size_t)B_ * NA_ * NMAX_ * 4)       // 5,120,000
#define REC_OFF   (CSN_OFF + CSN_BYTES)
#define REC_BYTES ((size_t)B_ * NM_ * 16)              // 9,600,000
#define RT_OFF    (REC_OFF + REC_BYTES)
#define RT_BYTES  ((size_t)B_ * NMAX_ * NM_ * 2)       // 38,400,000 (transposed R)
#define ST_OFF    (RT_OFF + RT_BYTES + 128)
#define ST_BYTES  ((size_t)B_ * (NA_ + 1) * 4 + 16)
#define WS_NEED   (ST_OFF + ST_BYTES)

// ---------------------------------------------------------------------------
// Kernel 0: segment starts from sorted iidx.
// ---------------------------------------------------------------------------
__global__ void starts_kernel(const int* __restrict__ iidx, int* __restrict__ starts) {
    int p = blockIdx.x * blockDim.x + threadIdx.x;
    if (p >= B_ * NM_) return;
    int b = p / NM_, pl = p - b * NM_;
    const int* ii = iidx + (size_t)b * NM_;
    int* st = starts + (size_t)b * (NA_ + 1);
    int cur = ii[pl];
    int prev = (pl == 0) ? -1 : ii[pl - 1];
    for (int a = prev + 1; a <= cur; ++a) st[a] = pl;
    if (pl == NM_ - 1) {
        for (int a = cur + 1; a <= NA_; ++a) st[a] = NM_;
    }
}

// ---------------------------------------------------------------------------
// prep0: atom-parallel (half-wave = one atom, lane = pair offset within the
// segment). Computes dist/fcut/jat once per pair (per lane), then loops n
// with (alpha, rs) from LDS, writing the TRANSPOSED radial table:
//   R_T[b][n][p] = fcut * exp(alpha[jat][n] * (dist - rs[jat][n])^2)   (fp16)
// Column writes are 2B x seg contiguous (coalesced). Also writes
//   rec[p] = (x, y, z, bitcast(j | jat<<16)).
// Out-of-segment lanes are clamped to the last pair (duplicate same-value
// writes: benign).
// ---------------------------------------------------------------------------
__global__ __launch_bounds__(256) void prep0_kernel(
    const float* __restrict__ disp, const float* __restrict__ alpha,
    const float* __restrict__ rsp, const int* __restrict__ jidx,
    const int* __restrict__ sorted_numbers, const int* __restrict__ starts,
    unsigned short* __restrict__ RT, float4* __restrict__ rec)
{
    __shared__ float2 tab[NS_ * NMAX_];
    int tid = threadIdx.x;
    if (tid < NS_ * NMAX_) tab[tid] = make_float2(alpha[tid], rsp[tid]);
    __syncthreads();

    int wave = blockIdx.x * 4 + (tid >> 6);
    int lane = tid & 63;
    int h = lane >> 5, kn = lane & 31;
    int g = wave * 2 + h;
    if (g >= B_ * NA_) return;
    int b = g / NA_, a = g - b * NA_;

    const int* st = starts + b * (NA_ + 1);
    int p0 = st[a], p1 = st[a + 1];
    int seg = p1 - p0;

    const int* jjb = jidx + (size_t)b * NM_;
    const float* dpb = disp + (size_t)b * NM_ * 3;
    unsigned short* RTb = RT + (size_t)b * NMAX_ * NM_;
    float4* recb = rec + (size_t)b * NM_;

    for (int kb = 0; kb < seg; kb += 32) {
        int k = kb + kn;
        int kc = (k < seg) ? k : (seg - 1);
        int p = p0 + kc;
        int j = jjb[p];
        float x = dpb[p * 3 + 0];
        float y = dpb[p * 3 + 1];
        float z = dpb[p * 3 + 2];
        int jat = sorted_numbers[j];
        float dist = sqrtf(x * x + y * y + z * z);
        float c = __cosf(dist * (PI_F / 6.0f));
        float fc = 0.25f * (c + 1.f) * (c + 1.f);
        recb[p] = make_float4(x, y, z, __int_as_float(j | (jat << 16)));
        const float2* trow = tab + jat * NMAX_;
        unsigned short* col = RTb + p;
#pragma unroll 8
        for (int nn = 0; nn < NMAX_; ++nn) {
            float2 ar = trow[nn];
            float dd = dist - ar.y;
            float e = __expf(ar.x * dd * dd);
            col[(size_t)nn * NM_] = __half_as_ushort(__float2half_rn(fc * e));
        }
    }
}

// ---------------------------------------------------------------------------
// pass: one wave = TWO atoms (half-wave each, lane = n). All loads issued in
// the prologue (independent): R window as dwords from the transposed row,
// rec lane-owned + shfl-distributed, (PASS1) csn2 rows gathered per pair.
// Compute loop is a fully static macro unroll of 32 pairs with wave-uniform
// group guards; per-lane validity via cndmask. Rare seg>32 -> scalar tail.
// PASS=0: coef = R * spp[jat][n]; epilogue MLP -> csn2.
// PASS=1: coef = R * csn2[j][n];  epilogue rho -> out.
// ---------------------------------------------------------------------------
template <int PASS>
__global__ __launch_bounds__(256) void pass_kernel(
    const unsigned short* __restrict__ RT, const float4* __restrict__ rec,
    const float* __restrict__ spp, const float* __restrict__ op,
    const float* __restrict__ w1, const float* __restrict__ b1,
    const float* __restrict__ w2, const float* __restrict__ b2,
    const float* __restrict__ w3, const float* __restrict__ b3,
    const int* __restrict__ sorted_numbers, const int* __restrict__ starts,
    float* __restrict__ csn2, float* __restrict__ out)
{
    int wave = blockIdx.x * 4 + (threadIdx.x >> 6);
    int lane = threadIdx.x & 63;
    int h = lane >> 5, n = lane & 31;
    int g = wave * 2 + h;
    if (g >= B_ * NA_) return;
    int b = g / NA_, a = g - b * NA_;

    const int* st = starts + b * (NA_ + 1);
    int p0 = st[a], p1 = st[a + 1];
    int seg = p1 - p0;
    int oseg = __shfl_xor(seg, 32);
    int mseg = (seg > oseg) ? seg : oseg;   // wave-uniform

    const unsigned short* RTrow = RT + ((size_t)b * NMAX_ + n) * NM_;
    const float4* recb = rec + (size_t)b * NM_;
    const float* csb = csn2 + (size_t)b * NA_ * NMAX_;

    // rec ownership: lane L holds rec[p0_of_its_half + (L&31)]
    int rmax = (seg > 0) ? (p1 - 1) : ((p0 < NM_) ? p0 : NM_ - 1);
    int ri = p0 + n;
    if (ri > rmax) ri = rmax;
    float4 rv = recb[ri];

    // R dword window (gated groups, clamped for safety)
    int P = p0 & 1;
    const unsigned int* Rd = (const unsigned int*)RTrow;
    int wb = (p0 - P) >> 1;
    const int dmax = NM_ / 2 - 1;
    unsigned int d[17];
#define LDD(i) { int ii_ = wb + (i); if (ii_ > dmax) ii_ = dmax; d[(i)] = Rd[ii_]; }
    LDD(0) LDD(1) LDD(2) LDD(3) LDD(4)
    if (mseg > 8)  { LDD(5) LDD(6) LDD(7) LDD(8) }
    else { d[5] = d[6] = d[7] = d[8] = 0u; }
    if (mseg > 16) { LDD(9) LDD(10) LDD(11) LDD(12) }
    else { d[9] = d[10] = d[11] = d[12] = 0u; }
    if (mseg > 24) { LDD(13) LDD(14) LDD(15) LDD(16) }
    else { d[13] = d[14] = d[15] = d[16] = 0u; }
#undef LDD

    float sp0, sp1, sp2, sp3;
    sp0 = spp[n]; sp1 = spp[32 + n]; sp2 = spp[64 + n]; sp3 = spp[96 + n];

    const float* opb = op + (size_t)PASS * 2 * NMAX_ * NO_;
    float W0[NO_], W1[NO_];
#pragma unroll
    for (int o = 0; o < NO_; ++o) {
        W0[o] = opb[(0 * NMAX_ + n) * NO_ + o];
        W1[o] = opb[(1 * NMAX_ + n) * NO_ + o];
    }

    int hb = lane & 32;                 // shfl base for this half
    int segc = (seg > 0) ? seg - 1 : 0;

    float cj[32];
    if constexpr (PASS == 1) {
#define LC(k) { int kc_ = ((k) < seg) ? (k) : segc;                          \
                int wj_ = __float_as_int(__shfl(rv.w, hb + kc_));            \
                cj[(k)] = csb[(size_t)(wj_ & 0xffff) * NMAX_ + n]; }
        LC(0) LC(1) LC(2) LC(3) LC(4) LC(5) LC(6) LC(7)
        if (mseg > 8)  { LC(8) LC(9) LC(10) LC(11) LC(12) LC(13) LC(14) LC(15) }
        else { cj[8]=cj[9]=cj[10]=cj[11]=cj[12]=cj[13]=cj[14]=cj[15]=0.f; }
        if (mseg > 16) { LC(16) LC(17) LC(18) LC(19) LC(20) LC(21) LC(22) LC(23) }
        else { cj[16]=cj[17]=cj[18]=cj[19]=cj[20]=cj[21]=cj[22]=cj[23]=0.f; }
        if (mseg > 24) { LC(24) LC(25) LC(26) LC(27) LC(28) LC(29) LC(30) LC(31) }
        else { cj[24]=cj[25]=cj[26]=cj[27]=cj[28]=cj[29]=cj[30]=cj[31]=0.f; }
#undef LC
    }

    float acc0 = 0.f, acc1 = 0.f, acc2 = 0.f, acc3 = 0.f;
    int shEven = P << 4;
    int shOdd  = (P ^ 1) << 4;

#define KK(k) {                                                              \
    unsigned int w_ = (((k) & 1) == 0) ? d[(k) >> 1]                         \
                      : (P ? d[((k) + 1) >> 1] : d[(k) >> 1]);               \
    int sh_ = (((k) & 1) == 0) ? shEven : shOdd;                             \
    float rf_ = __half2float(__ushort_as_half(                               \
                    (unsigned short)((w_ >> sh_) & 0xffffu)));               \
    float xk_ = __shfl(rv.x, hb + (k));                                      \
    float yk_ = __shfl(rv.y, hb + (k));                                      \
    float zk_ = __shfl(rv.z, hb + (k));                                      \
    float coef_;                                                             \
    if constexpr (PASS == 0) {                                               \
        int wj_ = __float_as_int(__shfl(rv.w, hb + (k)));                    \
        int jat_ = (wj_ >> 16) & 3;                                          \
        float cjv_ = (jat_ & 2) ? ((jat_ & 1) ? sp3 : sp2)                   \
                                : ((jat_ & 1) ? sp1 : sp0);                  \
        coef_ = rf_ * cjv_;                                                  \
    } else {                                                                 \
        coef_ = rf_ * cj[(k)];                                               \
    }                                                                        \
    coef_ = ((k) < seg) ? coef_ : 0.f;                                       \
    acc0 += coef_;                                                           \
    acc1 = fmaf(coef_, xk_, acc1);                                           \
    acc2 = fmaf(coef_, yk_, acc2);                                           \
    acc3 = fmaf(coef_, zk_, acc3);                                           \
}
#define KK4(k0) if (mseg > (k0)) { KK(k0) KK((k0)+1) KK((k0)+2) KK((k0)+3) }
    KK4(0) KK4(4) KK4(8) KK4(12) KK4(16) KK4(20) KK4(24) KK4(28)
#undef KK4
#undef KK

    // rare tail: segments longer than 32 pairs
    for (int p = p0 + 32; p < p1; ++p) {
        float4 t = recb[p];
        float rf = __half2float(__ushort_as_half(RTrow[p]));
        int wj = __float_as_int(t.w);
        float coef;
        if constexpr (PASS == 0) {
            int jat = (wj >> 16) & 3;
            float cjv = (jat & 2) ? ((jat & 1) ? sp3 : sp2)
                                  : ((jat & 1) ? sp1 : sp0);
            coef = rf * cjv;
        } else {
            coef = rf * csb[(size_t)(wj & 0xffff) * NMAX_ + n];
        }
        acc0 += coef;
        acc1 = fmaf(coef, t.x, acc1);
        acc2 = fmaf(coef, t.y, acc2);
        acc3 = fmaf(coef, t.z, acc3);
    }

    // t[l][o] butterfly over the 32-lane half (each half = its own atom)
    float t[4][NO_];
#pragma unroll
    for (int o = 0; o < NO_; ++o) {
        t[0][o] = W0[o] * acc0;
        t[1][o] = W1[o] * acc1;
        t[2][o] = W1[o] * acc2;
        t[3][o] = W1[o] * acc3;
    }
#pragma unroll
    for (int off = 1; off < 32; off <<= 1) {
#pragma unroll
        for (int l = 0; l < 4; ++l)
#pragma unroll
            for (int o = 0; o < NO_; ++o)
                t[l][o] += __shfl_xor(t[l][o], off);
    }
    float rho[NO_];
#pragma unroll
    for (int o = 0; o < NO_; ++o)
        rho[o] = t[0][o] * t[0][o] + t[1][o] * t[1][o] +
                 t[2][o] * t[2][o] + t[3][o] * t[3][o];

    if constexpr (PASS == 1) {
        if (n == 0) {
            *reinterpret_cast<float4*>(out + (size_t)g * NO_) =
                make_float4(rho[0], rho[1], rho[2], rho[3]);
        }
    } else {
        // MLP: rho(4) -> h1(4,tanh) -> h2(38,tanh) -> 32, per atom-half
        float h1v[H1_];
#pragma unroll
        for (int k = 0; k < H1_; ++k) {
            float s = b1[k];
#pragma unroll
            for (int o = 0; o < NO_; ++o) s = fmaf(rho[o], w1[o * H1_ + k], s);
            h1v[k] = tanhf(s);
        }
        float sa = b2[n];
        int jbi = 32 + (n < 6 ? n : 5);
        float sb = b2[jbi];
#pragma unroll
        for (int k = 0; k < H1_; ++k) {
            sa = fmaf(h1v[k], w2[k * H2_ + n], sa);
            sb = fmaf(h1v[k], w2[k * H2_ + jbi], sb);
        }
        float hva = tanhf(sa);
        float hvb = tanhf(sb);
        float on = b3[n];
#pragma unroll
        for (int j2 = 0; j2 < 32; ++j2) {
            float hj = __shfl(hva, hb + j2);
            on = fmaf(hj, w3[j2 * NMAX_ + n], on);
        }
#pragma unroll
        for (int j2 = 0; j2 < 6; ++j2) {
            float hj = __shfl(hvb, hb + j2);
            on = fmaf(hj, w3[(32 + j2) * NMAX_ + n], on);
        }
        int aat = sorted_numbers[a];
        float basev = (aat & 2) ? ((aat & 1) ? sp3 : sp2)
                                : ((aat & 1) ? sp1 : sp0);
        csn2[(size_t)g * NMAX_ + n] = basev + on;
    }
}

// ---------------------------------------------------------------------------
// Fallback pass kernel (round-2 proven) — used if ws_size too small.
// ---------------------------------------------------------------------------
template <int PASS>
__global__ __launch_bounds__(256) void fb_pass_kernel(
    const float* __restrict__ disp, const float* __restrict__ alpha,
    const float* __restrict__ rsp, const float* __restrict__ spp,
    const float* __restrict__ op, const float* __restrict__ w1,
    const float* __restrict__ b1, const float* __restrict__ w2,
    const float* __restrict__ b2, const float* __restrict__ w3,
    const float* __restrict__ b3, const int* __restrict__ jidx,
    const int* __restrict__ sorted_numbers, const int* __restrict__ starts,
    float* __restrict__ csn2, float* __restrict__ out)
{
    int wave = blockIdx.x * 4 + (threadIdx.x >> 6);
    int lane = threadIdx.x & 63;
    int h = lane >> 5;
    int n = lane & 31;
    int g = wave * 2 + h;
    if (g >= B_ * NA_) return;
    int b = g / NA_, a = g - b * NA_;

    float al[NS_], rv[NS_], spv[NS_];
#pragma unroll
    for (int s = 0; s < NS_; ++s) {
        al[s] = alpha[s * NMAX_ + n];
        rv[s] = rsp[s * NMAX_ + n];
        spv[s] = spp[s * NMAX_ + n];
    }
    const float* opb = op + (size_t)PASS * 2 * NMAX_ * NO_;
    float W0[NO_], W1[NO_];
#pragma unroll
    for (int o = 0; o < NO_; ++o) {
        W0[o] = opb[(0 * NMAX_ + n) * NO_ + o];
        W1[o] = opb[(1 * NMAX_ + n) * NO_ + o];
    }
    const int* st = starts + b * (NA_ + 1);
    int p0 = st[a], p1 = st[a + 1];
    const int* jjb = jidx + (size_t)b * NM_;
    const float* dpb = disp + (size_t)b * NM_ * 3;
    const float* csb = csn2 + (size_t)b * NA_ * NMAX_;

    float acc0 = 0.f, acc1 = 0.f, acc2 = 0.f, acc3 = 0.f;
    for (int p = p0; p < p1; ++p) {
        int j = jjb[p];
        float x = dpb[p * 3 + 0], y = dpb[p * 3 + 1], z = dpb[p * 3 + 2];
        float dist = sqrtf(x * x + y * y + z * z);
        float c = __cosf(dist * (PI_F / 6.0f));
        float fcv = 0.25f * (c + 1.f) * (c + 1.f);
        int jat = sorted_numbers[j];
        bool s0 = (jat & 1) != 0, s1 = (jat & 2) != 0;
        float av = s1 ? (s0 ? al[3] : al[2]) : (s0 ? al[1] : al[0]);
        float rsv = s1 ? (s0 ? rv[3] : rv[2]) : (s0 ? rv[1] : rv[0]);
        float cjv;
        if constexpr (PASS == 0)
            cjv = s1 ? (s0 ? spv[3] : spv[2]) : (s0 ? spv[1] : spv[0]);
        else
            cjv = csb[(size_t)j * NMAX_ + n];
        float dd = dist - rsv;
        float coef = fcv * cjv * __expf(av * dd * dd);
        acc0 += coef;
        acc1 = fmaf(coef, x, acc1);
        acc2 = fmaf(coef, y, acc2);
        acc3 = fmaf(coef, z, acc3);
    }
    float t[4][NO_];
#pragma unroll
    for (int o = 0; o < NO_; ++o) {
        t[0][o] = W0[o] * acc0; t[1][o] = W1[o] * acc1;
        t[2][o] = W1[o] * acc2; t[3][o] = W1[o] * acc3;
    }
#pragma unroll
    for (int off = 1; off < 32; off <<= 1) {
#pragma unroll
        for (int l = 0; l < 4; ++l)
#pragma unroll
            for (int o = 0; o < NO_; ++o)
                t[l][o] += __shfl_xor(t[l][o], off);
    }
    float rho[NO_];
#pragma unroll
    for (int o = 0; o < NO_; ++o)
        rho[o] = t[0][o] * t[0][o] + t[1][o] * t[1][o] +
                 t[2][o] * t[2][o] + t[3][o] * t[3][o];
    if constexpr (PASS == 1) {
        if (n == 0)
            *reinterpret_cast<float4*>(out + (size_t)g * NO_) =
                make_float4(rho[0], rho[1], rho[2], rho[3]);
    } else {
        float h1v[H1_];
#pragma unroll
        for (int k = 0; k < H1_; ++k) {
            float s = b1[k];
#pragma unroll
            for (int o = 0; o < NO_; ++o) s = fmaf(rho[o], w1[o * H1_ + k], s);
            h1v[k] = tanhf(s);
        }
        float sa = b2[n];
        int jbi = 32 + (n < 6 ? n : 5);
        float sb = b2[jbi];
#pragma unroll
        for (int k = 0; k < H1_; ++k) {
            sa = fmaf(h1v[k], w2[k * H2_ + n], sa);
            sb = fmaf(h1v[k], w2[k * H2_ + jbi], sb);
        }
        float hva = tanhf(sa), hvb = tanhf(sb);
        float on = b3[n];
        int base_lane = h << 5;
#pragma unroll
        for (int j2 = 0; j2 < 32; ++j2)
            on = fmaf(__shfl(hva, base_lane + j2), w3[j2 * NMAX_ + n], on);
#pragma unroll
        for (int j2 = 0; j2 < 6; ++j2)
            on = fmaf(__shfl(hvb, base_lane + j2), w3[(32 + j2) * NMAX_ + n], on);
        int aat = sorted_numbers[a];
        bool t0b = (aat & 1) != 0, t1b = (aat & 2) != 0;
        float basev = t1b ? (t0b ? spv[3] : spv[2]) : (t0b ? spv[1] : spv[0]);
        csn2[(size_t)g * NMAX_ + n] = basev + on;
    }
}

extern "C" void kernel_launch(void* const* d_in, const int* in_sizes, int n_in,
                              void* d_out, int out_size, void* d_ws, size_t ws_size,
                              hipStream_t stream) {
    const float* disp = (const float*)d_in[0];
    const float* alpha = (const float*)d_in[1];
    const float* rsp = (const float*)d_in[2];
    const float* spp = (const float*)d_in[3];
    const float* op = (const float*)d_in[4];
    const float* w1 = (const float*)d_in[5];
    const float* b1 = (const float*)d_in[6];
    const float* w2 = (const float*)d_in[7];
    const float* b2 = (const float*)d_in[8];
    const float* w3 = (const float*)d_in[9];
    const float* b3 = (const float*)d_in[10];
    const int* iidx = (const int*)d_in[11];
    const int* jidx = (const int*)d_in[12];
    const int* sn = (const int*)d_in[13];
    float* out = (float*)d_out;

    int nthr = B_ * NM_;

    if (ws_size >= WS_NEED) {
        float* csn2 = (float*)((char*)d_ws + CSN_OFF);
        float4* rec = (float4*)((char*)d_ws + REC_OFF);
        unsigned short* RT = (unsigned short*)((char*)d_ws + RT_OFF);
        int* starts = (int*)((char*)d_ws + ST_OFF);

        starts_kernel<<<(nthr + 255) / 256, 256, 0, stream>>>(iidx, starts);
        int ablocks = (B_ * NA_) / 8;     // 2 atoms/wave, 4 waves/block = 5000
        prep0_kernel<<<ablocks, 256, 0, stream>>>(disp, alpha, rsp, jidx, sn,
                                                  starts, RT, rec);
        pass_kernel<0><<<ablocks, 256, 0, stream>>>(RT, rec, spp, op, w1, b1, w2,
                                                    b2, w3, b3, sn, starts, csn2, out);
        pass_kernel<1><<<ablocks, 256, 0, stream>>>(RT, rec, spp, op, w1, b1, w2,
                                                    b2, w3, b3, sn, starts, csn2, out);
    } else {
        float* csn2 = (float*)d_ws;
        int* starts = (int*)((char*)d_ws + CSN_BYTES);
        int nblocks = ((B_ * NA_) / 2 + 3) / 4;
        starts_kernel<<<(nthr + 255) / 256, 256, 0, stream>>>(iidx, starts);
        fb_pass_kernel<0><<<nblocks, 256, 0, stream>>>(disp, alpha, rsp, spp, op,
                                                       w1, b1, w2, b2, w3, b3,
                                                       jidx, sn, starts, csn2, out);
        fb_pass_kernel<1><<<nblocks, 256, 0, stream>>>(disp, alpha, rsp, spp, op,
                                                       w1, b1, w2, b2, w3, b3,
                                                       jidx, sn, starts, csn2, out);
    }
}